// Round 1
// baseline (1605.316 us; speedup 1.0000x reference)
//
#include <hip/hip_runtime.h>

#define H 100
#define B 16
#define S 256
#define V 32000
#define NROW (B*S)   // 4096

// ---------------------------------------------------------------------------
// K1: xpart[row][j] = emb[x[row]] @ W_ih[:,j] + b_ih[j] + b_hh[j]
// ---------------------------------------------------------------------------
__global__ __launch_bounds__(128) void k_embed_xpart(
    const int* __restrict__ x, const float* __restrict__ emb,
    const float* __restrict__ Wih, const float* __restrict__ bih,
    const float* __restrict__ bhh, float* __restrict__ xpart)
{
    int row = blockIdx.x;
    int j = threadIdx.x;
    __shared__ __align__(16) float e_s[104];
    int tok = x[row];
    if (j < H) e_s[j] = emb[tok * H + j];
    __syncthreads();
    if (j >= H) return;
    float acc = bih[j] + bhh[j];
    const float4* e4 = (const float4*)e_s;
#pragma unroll
    for (int kk = 0; kk < 25; kk++) {
        float4 ev = e4[kk];
        acc = fmaf(ev.x, Wih[(4*kk+0)*H + j], acc);
        acc = fmaf(ev.y, Wih[(4*kk+1)*H + j], acc);
        acc = fmaf(ev.z, Wih[(4*kk+2)*H + j], acc);
        acc = fmaf(ev.w, Wih[(4*kk+3)*H + j], acc);
    }
    xpart[row * H + j] = acc;
}

// ---------------------------------------------------------------------------
// K2: sequential scan. One block per batch. Thread j holds W_hh[:,j] in
// registers (100 VGPRs); h broadcast through LDS double buffer.
// ---------------------------------------------------------------------------
__global__ __launch_bounds__(128) void k_rnn_scan(
    const float* __restrict__ xpart, const float* __restrict__ h0,
    const float* __restrict__ Whh, float* __restrict__ hs,
    float* __restrict__ hlast)
{
    int b = blockIdx.x;
    int j = threadIdx.x;
    __shared__ __align__(16) float hbuf[2][128];
    float w[H];
    if (j < H) {
#pragma unroll
        for (int k = 0; k < H; k++) w[k] = Whh[k * H + j];   // coalesced over j
        hbuf[0][j] = h0[b * H + j];
    }
    __syncthreads();
    float xp = (j < H) ? xpart[(b * S + 0) * H + j] : 0.f;   // prefetch t=0
    int p = 0;
    for (int t = 0; t < S; t++) {
        float acc = xp;
        if (j < H && t + 1 < S) xp = xpart[(b * S + t + 1) * H + j]; // prefetch
        if (j < H) {
            const float4* h4 = (const float4*)hbuf[p];
#pragma unroll
            for (int kk = 0; kk < 25; kk++) {
                float4 hv = h4[kk];
                acc = fmaf(hv.x, w[4*kk+0], acc);
                acc = fmaf(hv.y, w[4*kk+1], acc);
                acc = fmaf(hv.z, w[4*kk+2], acc);
                acc = fmaf(hv.w, w[4*kk+3], acc);
            }
            // tanh via exp, clamped so e never overflows
            float xc = fminf(fmaxf(acc, -15.f), 15.f);
            float e = __expf(2.f * xc);
            float hnew = (e - 1.f) / (e + 1.f);
            hs[(b * S + t) * H + j] = hnew;
            hbuf[p ^ 1][j] = hnew;
        }
        __syncthreads();
        p ^= 1;
    }
    if (j < H) hlast[b * H + j] = hbuf[p][j];
}

// ---------------------------------------------------------------------------
// K3: logits GEMM [4096,100]x[100,32000] + b_fc, writes logits to d_out and
// accumulates per-row sum(exp(logit)) (no max needed: |logit| <= ~10.1).
// Tile: 32 rows x 512 cols per block (2 cols/thread), hs tile in LDS.
// ---------------------------------------------------------------------------
__global__ __launch_bounds__(256) void k_logits(
    const float* __restrict__ hs, const float* __restrict__ Wfc,
    const float* __restrict__ bfc, float* __restrict__ out,
    float* __restrict__ sumexp)
{
    __shared__ __align__(16) float hsS[32 * H];   // 3200 floats, contiguous rows
    int r0 = blockIdx.y * 32;
    const float* src = hs + (long long)r0 * H;
    for (int i = threadIdx.x; i < 32 * H; i += 256) hsS[i] = src[i];
    __syncthreads();

    int v0 = blockIdx.x * 512 + threadIdx.x;      // always < V (63*512-256+255)
    int v1 = v0 + 256;
    bool g1 = (v1 < V);

    float acc0[32], acc1[32];
#pragma unroll
    for (int m = 0; m < 32; m++) { acc0[m] = 0.f; acc1[m] = 0.f; }

    for (int k0 = 0; k0 < H; k0 += 4) {
        float w00 = Wfc[(k0+0)*V + v0];
        float w01 = Wfc[(k0+1)*V + v0];
        float w02 = Wfc[(k0+2)*V + v0];
        float w03 = Wfc[(k0+3)*V + v0];
        float w10 = g1 ? Wfc[(k0+0)*V + v1] : 0.f;
        float w11 = g1 ? Wfc[(k0+1)*V + v1] : 0.f;
        float w12 = g1 ? Wfc[(k0+2)*V + v1] : 0.f;
        float w13 = g1 ? Wfc[(k0+3)*V + v1] : 0.f;
#pragma unroll
        for (int m = 0; m < 32; m++) {
            float4 hv = *(const float4*)&hsS[m * H + k0];  // broadcast, no conflict
            acc0[m] = fmaf(hv.x, w00, acc0[m]);
            acc0[m] = fmaf(hv.y, w01, acc0[m]);
            acc0[m] = fmaf(hv.z, w02, acc0[m]);
            acc0[m] = fmaf(hv.w, w03, acc0[m]);
            acc1[m] = fmaf(hv.x, w10, acc1[m]);
            acc1[m] = fmaf(hv.y, w11, acc1[m]);
            acc1[m] = fmaf(hv.z, w12, acc1[m]);
            acc1[m] = fmaf(hv.w, w13, acc1[m]);
        }
    }

    float b0 = bfc[v0];
    float b1 = g1 ? bfc[v1] : 0.f;
    int lane = threadIdx.x & 63;
#pragma unroll
    for (int m = 0; m < 32; m++) {
        float l0 = acc0[m] + b0;
        float l1 = acc1[m] + b1;
        long long base = (long long)(r0 + m) * V;
        out[base + v0] = l0;
        if (g1) out[base + v1] = l1;
        float e = __expf(l0) + (g1 ? __expf(l1) : 0.f);
#pragma unroll
        for (int sft = 32; sft > 0; sft >>= 1) e += __shfl_xor(e, sft);
        if (lane == 0) atomicAdd(&sumexp[r0 + m], e);
    }
}

// ---------------------------------------------------------------------------
// K4: lse[row] = log(sumexp[row])
// ---------------------------------------------------------------------------
__global__ void k_lse(const float* __restrict__ sumexp, float* __restrict__ lse)
{
    int i = blockIdx.x * 256 + threadIdx.x;
    if (i < NROW) lse[i] = logf(sumexp[i]);
}

// ---------------------------------------------------------------------------
// K5: out[row][v] -= lse[row], float4 over the whole 524MB
// ---------------------------------------------------------------------------
__global__ __launch_bounds__(256) void k_sub(
    float4* __restrict__ out, const float* __restrict__ lse)
{
    int row = blockIdx.y;
    int c = blockIdx.x * 256 + threadIdx.x;
    if (c < V / 4) {
        float l = lse[row];
        long long i = (long long)row * (V / 4) + c;
        float4 v = out[i];
        v.x -= l; v.y -= l; v.z -= l; v.w -= l;
        out[i] = v;
    }
}

extern "C" void kernel_launch(void* const* d_in, const int* in_sizes, int n_in,
                              void* d_out, int out_size, void* d_ws, size_t ws_size,
                              hipStream_t stream)
{
    const int*   x    = (const int*)d_in[0];
    const float* h0   = (const float*)d_in[1];
    const float* emb  = (const float*)d_in[2];
    const float* Wih  = (const float*)d_in[3];
    const float* Whh  = (const float*)d_in[4];
    const float* bih  = (const float*)d_in[5];
    const float* bhh  = (const float*)d_in[6];
    const float* Wfc  = (const float*)d_in[7];
    const float* bfc  = (const float*)d_in[8];

    float* out   = (float*)d_out;
    float* hlast = out + (long long)NROW * V;

    float* xpart  = (float*)d_ws;            // 409600 f
    float* hsbuf  = xpart + NROW * H;        // 409600 f
    float* sumexp = hsbuf + NROW * H;        // 4096 f
    float* lse    = sumexp + NROW;           // 4096 f

    hipMemsetAsync(sumexp, 0, NROW * sizeof(float), stream);
    k_embed_xpart<<<NROW, 128, 0, stream>>>(x, emb, Wih, bih, bhh, xpart);
    k_rnn_scan<<<B, 128, 0, stream>>>(xpart, h0, Whh, hsbuf, hlast);
    k_logits<<<dim3(63, NROW / 32), 256, 0, stream>>>(hsbuf, Wfc, bfc, out, sumexp);
    k_lse<<<(NROW + 255) / 256, 256, 0, stream>>>(sumexp, lse);
    k_sub<<<dim3(32, NROW), 256, 0, stream>>>((float4*)out, lse);
}

// Round 2
// 1198.035 us; speedup vs baseline: 1.3400x; 1.3400x over previous
//
#include <hip/hip_runtime.h>

#define H 100
#define B 16
#define S 256
#define V 32000
#define NROW (B*S)   // 4096
#define KP 128       // K padded to 128 for 4x mfma_16x16x32

typedef __attribute__((ext_vector_type(8))) short short8;   // 8 bf16 = 4 VGPRs
typedef __attribute__((ext_vector_type(4))) float f32x4;

static __device__ __forceinline__ unsigned short f2bf(float f) {
    unsigned u = __float_as_uint(f);
    u += 0x7FFF + ((u >> 16) & 1);    // round-to-nearest-even
    return (unsigned short)(u >> 16);
}
static __device__ __forceinline__ unsigned pack2(float a, float b) {
    return (unsigned)f2bf(a) | ((unsigned)f2bf(b) << 16);
}

// ---------------------------------------------------------------------------
// K0: transpose+cast Wfc [100][V] f32 -> WfcT [V][128] bf16 (k 100..127 = 0)
// Reads coalesced (64 consecutive v per wave per k).
// ---------------------------------------------------------------------------
__global__ __launch_bounds__(256) void k_wfcT(const float* __restrict__ Wfc,
                                              unsigned short* __restrict__ WfcT)
{
    int v = blockIdx.x * 256 + threadIdx.x;   // grid 125*256 = 32000 exact
    float w[100];
#pragma unroll
    for (int k = 0; k < 100; k++) w[k] = Wfc[(long long)k * V + v];
    unsigned* dst = (unsigned*)(WfcT + (long long)v * KP);
#pragma unroll
    for (int q = 0; q < 12; q++) {
        uint4 o;
        o.x = pack2(w[q*8+0], w[q*8+1]);
        o.y = pack2(w[q*8+2], w[q*8+3]);
        o.z = pack2(w[q*8+4], w[q*8+5]);
        o.w = pack2(w[q*8+6], w[q*8+7]);
        *(uint4*)(dst + q*4) = o;
    }
    uint2 t;
    t.x = pack2(w[96], w[97]);
    t.y = pack2(w[98], w[99]);
    *(uint2*)(dst + 48) = t;
    *(uint2*)(dst + 50) = make_uint2(0,0);
    *(uint4*)(dst + 52) = make_uint4(0,0,0,0);
    *(uint4*)(dst + 56) = make_uint4(0,0,0,0);
    *(uint4*)(dst + 60) = make_uint4(0,0,0,0);
}

// ---------------------------------------------------------------------------
// K1: xpart[row][j] = emb[x[row]] @ W_ih[:,j] + b_ih[j] + b_hh[j]
// ---------------------------------------------------------------------------
__global__ __launch_bounds__(128) void k_embed_xpart(
    const int* __restrict__ x, const float* __restrict__ emb,
    const float* __restrict__ Wih, const float* __restrict__ bih,
    const float* __restrict__ bhh, float* __restrict__ xpart)
{
    int row = blockIdx.x;
    int j = threadIdx.x;
    __shared__ __align__(16) float e_s[104];
    int tok = x[row];
    if (j < H) e_s[j] = emb[tok * H + j];
    __syncthreads();
    if (j >= H) return;
    float acc = bih[j] + bhh[j];
    const float4* e4 = (const float4*)e_s;
#pragma unroll
    for (int kk = 0; kk < 25; kk++) {
        float4 ev = e4[kk];
        acc = fmaf(ev.x, Wih[(4*kk+0)*H + j], acc);
        acc = fmaf(ev.y, Wih[(4*kk+1)*H + j], acc);
        acc = fmaf(ev.z, Wih[(4*kk+2)*H + j], acc);
        acc = fmaf(ev.w, Wih[(4*kk+3)*H + j], acc);
    }
    xpart[row * H + j] = acc;
}

// ---------------------------------------------------------------------------
// K2: sequential scan; writes hs directly as padded bf16 [row][128].
// ---------------------------------------------------------------------------
__global__ __launch_bounds__(128) void k_rnn_scan(
    const float* __restrict__ xpart, const float* __restrict__ h0,
    const float* __restrict__ Whh, unsigned short* __restrict__ hsB,
    float* __restrict__ hlast)
{
    int b = blockIdx.x;
    int j = threadIdx.x;
    __shared__ __align__(16) float hbuf[2][128];
    float w[H];
    if (j < H) {
#pragma unroll
        for (int k = 0; k < H; k++) w[k] = Whh[k * H + j];   // coalesced over j
        hbuf[0][j] = h0[b * H + j];
    }
    __syncthreads();
    float xp = (j < H) ? xpart[(b * S + 0) * H + j] : 0.f;
    int p = 0;
    for (int t = 0; t < S; t++) {
        float acc = xp;
        if (j < H && t + 1 < S) xp = xpart[(b * S + t + 1) * H + j];
        if (j < H) {
            const float4* h4 = (const float4*)hbuf[p];
#pragma unroll
            for (int kk = 0; kk < 25; kk++) {
                float4 hv = h4[kk];
                acc = fmaf(hv.x, w[4*kk+0], acc);
                acc = fmaf(hv.y, w[4*kk+1], acc);
                acc = fmaf(hv.z, w[4*kk+2], acc);
                acc = fmaf(hv.w, w[4*kk+3], acc);
            }
            float xc = fminf(fmaxf(acc, -15.f), 15.f);
            float e = __expf(2.f * xc);
            float hnew = (e - 1.f) / (e + 1.f);
            hsB[(b * S + t) * KP + j] = f2bf(hnew);
            hbuf[p ^ 1][j] = hnew;
        } else {
            hsB[(b * S + t) * KP + j] = 0;   // zero the K-pad (ws is poisoned)
        }
        __syncthreads();
        p ^= 1;
    }
    if (j < H) hlast[b * H + j] = hbuf[p][j];
}

// ---------------------------------------------------------------------------
// K3: pass 1 — MFMA GEMM, accumulate per-row sum(exp(logit)), no logit write.
// Grid (8 col-chunks of 4000, 64 row-blocks of 64). Wave = 16 rows.
// A layout: A[m=lane&15][k=quad*8+j]; B[k=quad*8+j][n=lane&15];
// C/D: col=lane&15, row=quad*4+reg.
// ---------------------------------------------------------------------------
__global__ __launch_bounds__(256) void k_sumexp(
    const unsigned short* __restrict__ hsB, const unsigned short* __restrict__ WfcT,
    const float* __restrict__ bfc, float* __restrict__ sumexp)
{
    int lane = threadIdx.x & 63, wave = threadIdx.x >> 6;
    int quad = lane >> 4, l15 = lane & 15;
    int r0 = blockIdx.y * 64 + wave * 16;
    int n0 = blockIdx.x * 4000;
    const short8* aptr = (const short8*)(hsB + (long long)(r0 + l15) * KP + quad * 8);
    short8 a0 = aptr[0], a1 = aptr[4], a2 = aptr[8], a3 = aptr[12]; // k0=0,32,64,96
    float p0 = 0.f, p1 = 0.f, p2 = 0.f, p3 = 0.f;
    for (int nt = 0; nt < 250; nt++) {
        int col = n0 + nt * 16 + l15;
        const short8* bptr = (const short8*)(WfcT + (long long)col * KP + quad * 8);
        f32x4 acc = {0.f, 0.f, 0.f, 0.f};
        acc = __builtin_amdgcn_mfma_f32_16x16x32_bf16(a0, bptr[0],  acc, 0, 0, 0);
        acc = __builtin_amdgcn_mfma_f32_16x16x32_bf16(a1, bptr[4],  acc, 0, 0, 0);
        acc = __builtin_amdgcn_mfma_f32_16x16x32_bf16(a2, bptr[8],  acc, 0, 0, 0);
        acc = __builtin_amdgcn_mfma_f32_16x16x32_bf16(a3, bptr[12], acc, 0, 0, 0);
        float bias = bfc[col];
        p0 += __expf(acc[0] + bias);
        p1 += __expf(acc[1] + bias);
        p2 += __expf(acc[2] + bias);
        p3 += __expf(acc[3] + bias);
    }
#pragma unroll
    for (int m = 1; m <= 8; m <<= 1) {   // reduce over the 16 cols (lane&15)
        p0 += __shfl_xor(p0, m); p1 += __shfl_xor(p1, m);
        p2 += __shfl_xor(p2, m); p3 += __shfl_xor(p3, m);
    }
    if (l15 == 0) {
        int rr = r0 + quad * 4;
        atomicAdd(&sumexp[rr + 0], p0);
        atomicAdd(&sumexp[rr + 1], p1);
        atomicAdd(&sumexp[rr + 2], p2);
        atomicAdd(&sumexp[rr + 3], p3);
    }
}

// ---------------------------------------------------------------------------
// K4: lse[row] = log(sumexp[row])
// ---------------------------------------------------------------------------
__global__ void k_lse(const float* __restrict__ sumexp, float* __restrict__ lse)
{
    int i = blockIdx.x * 256 + threadIdx.x;
    if (i < NROW) lse[i] = logf(sumexp[i]);
}

// ---------------------------------------------------------------------------
// K5: pass 2 — MFMA GEMM again, write out = logit + bias - lse[row].
// Grid (125 col-blocks of 256, 64 row-blocks of 64).
// ---------------------------------------------------------------------------
__global__ __launch_bounds__(256) void k_out(
    const unsigned short* __restrict__ hsB, const unsigned short* __restrict__ WfcT,
    const float* __restrict__ bfc, const float* __restrict__ lse,
    float* __restrict__ out)
{
    int lane = threadIdx.x & 63, wave = threadIdx.x >> 6;
    int quad = lane >> 4, l15 = lane & 15;
    int r0 = blockIdx.y * 64 + wave * 16;
    int n0 = blockIdx.x * 256;
    const short8* aptr = (const short8*)(hsB + (long long)(r0 + l15) * KP + quad * 8);
    short8 a0 = aptr[0], a1 = aptr[4], a2 = aptr[8], a3 = aptr[12];
    f32x4 acc[16];
#pragma unroll
    for (int nt = 0; nt < 16; nt++) {
        const short8* bptr = (const short8*)(WfcT + (long long)(n0 + nt * 16 + l15) * KP + quad * 8);
        f32x4 c = {0.f, 0.f, 0.f, 0.f};
        c = __builtin_amdgcn_mfma_f32_16x16x32_bf16(a0, bptr[0],  c, 0, 0, 0);
        c = __builtin_amdgcn_mfma_f32_16x16x32_bf16(a1, bptr[4],  c, 0, 0, 0);
        c = __builtin_amdgcn_mfma_f32_16x16x32_bf16(a2, bptr[8],  c, 0, 0, 0);
        c = __builtin_amdgcn_mfma_f32_16x16x32_bf16(a3, bptr[12], c, 0, 0, 0);
        acc[nt] = c;
    }
    int rw = r0 + quad * 4;
    float ls0 = lse[rw + 0], ls1 = lse[rw + 1], ls2 = lse[rw + 2], ls3 = lse[rw + 3];
    long long rowbase = (long long)rw * V;
#pragma unroll
    for (int nt = 0; nt < 16; nt++) {
        int col = n0 + nt * 16 + l15;
        float bias = bfc[col];
        out[rowbase + col]            = acc[nt][0] + bias - ls0;
        out[rowbase + (long long)V + col]     = acc[nt][1] + bias - ls1;
        out[rowbase + 2LL * V + col]  = acc[nt][2] + bias - ls2;
        out[rowbase + 3LL * V + col]  = acc[nt][3] + bias - ls3;
    }
}

extern "C" void kernel_launch(void* const* d_in, const int* in_sizes, int n_in,
                              void* d_out, int out_size, void* d_ws, size_t ws_size,
                              hipStream_t stream)
{
    const int*   x    = (const int*)d_in[0];
    const float* h0   = (const float*)d_in[1];
    const float* emb  = (const float*)d_in[2];
    const float* Wih  = (const float*)d_in[3];
    const float* Whh  = (const float*)d_in[4];
    const float* bih  = (const float*)d_in[5];
    const float* bhh  = (const float*)d_in[6];
    const float* Wfc  = (const float*)d_in[7];
    const float* bfc  = (const float*)d_in[8];

    float* out   = (float*)d_out;
    float* hlast = out + (long long)NROW * V;

    float* xpart  = (float*)d_ws;                       // 409600 f32
    float* sumexp = xpart + NROW * H;                   // 4096 f32
    float* lse    = sumexp + NROW;                      // 4096 f32
    unsigned short* WfcT = (unsigned short*)(lse + NROW);      // V*128 bf16 = 8.192 MB
    unsigned short* hsB  = WfcT + (long long)V * KP;           // NROW*128 bf16 = 1.05 MB

    hipMemsetAsync(sumexp, 0, NROW * sizeof(float), stream);
    k_wfcT<<<V / 256, 256, 0, stream>>>(Wfc, WfcT);
    k_embed_xpart<<<NROW, 128, 0, stream>>>(x, emb, Wih, bih, bhh, xpart);
    k_rnn_scan<<<B, 128, 0, stream>>>(xpart, h0, Whh, hsB, hlast);
    k_sumexp<<<dim3(8, NROW / 64), 256, 0, stream>>>(hsB, WfcT, bfc, sumexp);
    k_lse<<<(NROW + 255) / 256, 256, 0, stream>>>(sumexp, lse);
    k_out<<<dim3(V / 256, NROW / 64), 256, 0, stream>>>(hsB, WfcT, bfc, lse, out);
}